// Round 10
// baseline (167.805 us; speedup 1.0000x reference)
//
#include <hip/hip_runtime.h>
#include <hip/hip_bf16.h>

// MDTA (multi-head cross attention with l2-normed q/k) for MI355X.
// B=8, N=4096, Ktok=256, C=512, H=8, D=64. Inputs f32, output f32.
//
// R8: 187.9us (serial GEMMs). R9: 153.1us (fusion+XCD swizzle; 2-phase dbuf
// was a wash -- barrier drain exposed HBM latency every BK=32 step).
// R10: 256x256-tile GEMMs, 8 waves, BK=64 (8 iters), LDS dbuf 128KB,
// reg-staged A+B with issue-early/write-late, XOR-swizzled LDS rows,
// 1 block/CU grids, bijective XCD swizzle.
//
// Pipeline (4 launches):
//  1) cvt_all:  Wq,Wk,Wv,Wo f32 -> bf16
//  2) proj_all: Q=l2norm(X@Wq^T), Kn=l2norm(S@Wk^T), Vt=(S@Wv^T)^T
//  3) attn:     O = softmax(temp * Q.K^T) @ V -> ws.Q (in place)
//  4) out_gemm: out = X + O @ Wo^T -> d_out (f32)

typedef __bf16 bf16;
typedef __attribute__((ext_vector_type(8))) __bf16 bf16x8;
typedef __attribute__((ext_vector_type(4))) float f32x4;

__device__ __forceinline__ unsigned pack2(float a, float b) {
  unsigned short x = __builtin_bit_cast(unsigned short, (bf16)a);
  unsigned short y = __builtin_bit_cast(unsigned short, (bf16)b);
  return (unsigned)x | ((unsigned)y << 16);
}

// ---------------------------------------------------------------------------
__global__ __launch_bounds__(256) void cvt_all(
    const float* __restrict__ Wq, const float* __restrict__ Wk,
    const float* __restrict__ Wv, const float* __restrict__ Wo,
    bf16* __restrict__ Wqb, bf16* __restrict__ Wkb, bf16* __restrict__ Wvb,
    bf16* __restrict__ Wob) {
  int i = blockIdx.x * 256 + threadIdx.x;  // chunk id, 32768 per weight
  int w = i >> 15, r = i & 32767;
  const float* src = (w == 0) ? Wq : (w == 1) ? Wk : (w == 2) ? Wv : Wo;
  bf16* dst = (w == 0) ? Wqb : (w == 1) ? Wkb : (w == 2) ? Wvb : Wob;
  float4 a = *(const float4*)(src + (size_t)r * 8);
  float4 b = *(const float4*)(src + (size_t)r * 8 + 4);
  uint4 v;
  v.x = pack2(a.x, a.y);
  v.y = pack2(a.z, a.w);
  v.z = pack2(b.x, b.y);
  v.w = pack2(b.z, b.w);
  *(uint4*)(dst + (size_t)r * 8) = v;
}

// ---------------------------------------------------------------------------
// Fused Q/K/V projection. 256x256 tile, 512 thr (8 waves 2x4: 128x64/wave),
// BK=64, 8 K-steps, LDS double-buffered (128 KB). A: f32 -> reg -> cvt ->
// swizzled ds_write (issue-early/write-late). B: bf16 -> reg -> swizzled
// ds_write. LDS rows are 128B; byte ^= ((row&7)<<4) kills the 32-way
// conflict on both ds_write_b128 and ds_read_b128 (attn-proven geometry).
// ---------------------------------------------------------------------------
__global__ __launch_bounds__(512, 2) void proj_all(
    const float* __restrict__ X, const float* __restrict__ S,
    const bf16* __restrict__ Wqb, const bf16* __restrict__ Wkb,
    const bf16* __restrict__ Wvb, bf16* __restrict__ Q,
    bf16* __restrict__ Kn, bf16* __restrict__ Vt) {
  __shared__ __align__(16) bf16 As[2][256 * 64];
  __shared__ __align__(16) bf16 Bs[2][256 * 64];

  // 288 blocks = 8 XCDs x 36; consecutive lg (the 2 n-tiles of an A panel)
  // share an XCD L2.
  const int lg = (blockIdx.x & 7) * 36 + (blockIdx.x >> 3);

  const float* A;
  const bf16* W;
  int m0, kind;  // 0=Q, 1=K, 2=V
  if (lg < 256) {
    kind = 0; A = X; W = Wqb; m0 = (lg >> 1) * 256;
  } else if (lg < 272) {
    kind = 1; A = S; W = Wkb; m0 = ((lg - 256) >> 1) * 256;
  } else {
    kind = 2; A = S; W = Wvb; m0 = ((lg - 272) >> 1) * 256;
  }
  const int n0 = (lg & 1) * 256;

  const int tid = threadIdx.x;
  const int wid = tid >> 6, lane = tid & 63;
  const int wr = wid >> 2, wc = wid & 3;
  const int g = lane >> 4, c16 = lane & 15;

  f32x4 acc[8][4] = {};

  // staging coords: chunk c = i*512 + tid -> row = c>>3 (0..255), kc = c&7
  // (8 bf16 = 16B per chunk); A chunk = 8 f32 (2 float4).
  // ---- prologue: stage K-tile 0 into buffer 0
#pragma unroll
  for (int i = 0; i < 4; ++i) {
    int c = i * 512 + tid, row = c >> 3, kc = c & 7;
    const float* s = A + (size_t)(m0 + row) * 512 + kc * 8;
    float4 x0 = *(const float4*)s, x1 = *(const float4*)(s + 4);
    uint4 v;
    v.x = pack2(x0.x, x0.y); v.y = pack2(x0.z, x0.w);
    v.z = pack2(x1.x, x1.y); v.w = pack2(x1.z, x1.w);
    int off = (row * 128 + kc * 16) ^ ((row & 7) << 4);
    *(uint4*)((char*)As[0] + off) = v;
    int4 wv = *(const int4*)(W + (size_t)(n0 + row) * 512 + kc * 8);
    *(int4*)((char*)Bs[0] + off) = wv;
  }
  __syncthreads();

  int cur = 0;
  for (int t = 0; t < 8; ++t) {
    float4 av[8];
    int4 bv[4];
    if (t < 7) {  // issue-early: global loads for t+1
      const int kb = (t + 1) * 64;
#pragma unroll
      for (int i = 0; i < 4; ++i) {
        int c = i * 512 + tid, row = c >> 3, kc = c & 7;
        const float* s = A + (size_t)(m0 + row) * 512 + kb + kc * 8;
        av[2 * i] = *(const float4*)s;
        av[2 * i + 1] = *(const float4*)(s + 4);
        bv[i] = *(const int4*)(W + (size_t)(n0 + row) * 512 + kb + kc * 8);
      }
    }

    // compute on buffer cur: 2 k-halves x (8 mi x 4 ni) MFMA
#pragma unroll
    for (int s = 0; s < 2; ++s) {
      bf16x8 af[8], bfr[4];
#pragma unroll
      for (int mi = 0; mi < 8; ++mi) {
        int row = wr * 128 + mi * 16 + c16;
        int off = (row * 128 + s * 64 + g * 16) ^ ((row & 7) << 4);
        af[mi] = *(const bf16x8*)((const char*)As[cur] + off);
      }
#pragma unroll
      for (int ni = 0; ni < 4; ++ni) {
        int col = wc * 64 + ni * 16 + c16;
        int off = (col * 128 + s * 64 + g * 16) ^ ((col & 7) << 4);
        bfr[ni] = *(const bf16x8*)((const char*)Bs[cur] + off);
      }
#pragma unroll
      for (int mi = 0; mi < 8; ++mi)
#pragma unroll
        for (int ni = 0; ni < 4; ++ni)
          acc[mi][ni] = __builtin_amdgcn_mfma_f32_16x16x32_bf16(
              af[mi], bfr[ni], acc[mi][ni], 0, 0, 0);
    }

    if (t < 7) {  // write-late: cvt + swizzled LDS store into back buffer
#pragma unroll
      for (int i = 0; i < 4; ++i) {
        int c = i * 512 + tid, row = c >> 3, kc = c & 7;
        uint4 v;
        v.x = pack2(av[2 * i].x, av[2 * i].y);
        v.y = pack2(av[2 * i].z, av[2 * i].w);
        v.z = pack2(av[2 * i + 1].x, av[2 * i + 1].y);
        v.w = pack2(av[2 * i + 1].z, av[2 * i + 1].w);
        int off = (row * 128 + kc * 16) ^ ((row & 7) << 4);
        *(uint4*)((char*)As[cur ^ 1] + off) = v;
        *(int4*)((char*)Bs[cur ^ 1] + off) = bv[i];
      }
    }
    __syncthreads();
    cur ^= 1;
  }

  // ---- epilogue. C/D frag: col = lane&15, row = (lane>>4)*4 + j   [m89]
  if (kind != 2) {
    bf16* C = (kind == 0) ? Q : Kn;
    // l2 norm over the wave's 64 cols (= exactly one head).
#pragma unroll
    for (int mi = 0; mi < 8; ++mi) {
      float ss[4];
#pragma unroll
      for (int j = 0; j < 4; ++j) {
        float s = 0.f;
#pragma unroll
        for (int ni = 0; ni < 4; ++ni) {
          float v = acc[mi][ni][j];
          s += v * v;
        }
        ss[j] = s;
      }
#pragma unroll
      for (int msk = 1; msk < 16; msk <<= 1)
#pragma unroll
        for (int j = 0; j < 4; ++j) ss[j] += __shfl_xor(ss[j], msk, 64);
      float inv[4];
#pragma unroll
      for (int j = 0; j < 4; ++j) inv[j] = rsqrtf(fmaxf(ss[j], 1e-24f));
#pragma unroll
      for (int ni = 0; ni < 4; ++ni)
#pragma unroll
        for (int j = 0; j < 4; ++j) {
          size_t idx = (size_t)(m0 + wr * 128 + mi * 16 + g * 4 + j) * 512 +
                       n0 + wc * 64 + ni * 16 + c16;
          C[idx] = (bf16)(acc[mi][ni][j] * inv[j]);
        }
    }
  } else {
    // transposed store into Vt[b][h][d][t] (M=2048): 4 j = 4 tokens -> 8B
#pragma unroll
    for (int mi = 0; mi < 8; ++mi) {
      int m = m0 + wr * 128 + mi * 16 + g * 4;  // +j
      int b = m >> 8, tt = m & 255;
#pragma unroll
      for (int ni = 0; ni < 4; ++ni) {
        int col = n0 + wc * 64 + ni * 16 + c16;
        int h = col >> 6, d = col & 63;
        uint2 v;
        v.x = pack2(acc[mi][ni][0], acc[mi][ni][1]);
        v.y = pack2(acc[mi][ni][2], acc[mi][ni][3]);
        *(uint2*)(Vt + ((size_t)((b * 8 + h) * 64 + d) * 256 + tt)) = v;
      }
    }
  }
}

// ---------------------------------------------------------------------------
// out = X + O @ Wo^T, f32 output. Same 256x256 / BK=64 / dbuf structure,
// both operands bf16 reg-staged with swizzled LDS.
// ---------------------------------------------------------------------------
__global__ __launch_bounds__(512, 2) void out_gemm(
    const bf16* __restrict__ O, const bf16* __restrict__ Wob,
    const float* __restrict__ Xres, float* __restrict__ out) {
  __shared__ __align__(16) bf16 As[2][256 * 64];
  __shared__ __align__(16) bf16 Bs[2][256 * 64];

  const int lg = (blockIdx.x & 7) * 32 + (blockIdx.x >> 3);  // 256 = 8x32
  const int m0 = (lg >> 1) * 256, n0 = (lg & 1) * 256;

  const int tid = threadIdx.x;
  const int wid = tid >> 6, lane = tid & 63;
  const int wr = wid >> 2, wc = wid & 3;
  const int g = lane >> 4, c16 = lane & 15;

  f32x4 acc[8][4] = {};

#pragma unroll
  for (int i = 0; i < 4; ++i) {
    int c = i * 512 + tid, row = c >> 3, kc = c & 7;
    int4 va = *(const int4*)(O + (size_t)(m0 + row) * 512 + kc * 8);
    int4 vb = *(const int4*)(Wob + (size_t)(n0 + row) * 512 + kc * 8);
    int off = (row * 128 + kc * 16) ^ ((row & 7) << 4);
    *(int4*)((char*)As[0] + off) = va;
    *(int4*)((char*)Bs[0] + off) = vb;
  }
  __syncthreads();

  int cur = 0;
  for (int t = 0; t < 8; ++t) {
    int4 av[4], bv[4];
    if (t < 7) {
      const int kb = (t + 1) * 64;
#pragma unroll
      for (int i = 0; i < 4; ++i) {
        int c = i * 512 + tid, row = c >> 3, kc = c & 7;
        av[i] = *(const int4*)(O + (size_t)(m0 + row) * 512 + kb + kc * 8);
        bv[i] = *(const int4*)(Wob + (size_t)(n0 + row) * 512 + kb + kc * 8);
      }
    }
#pragma unroll
    for (int s = 0; s < 2; ++s) {
      bf16x8 af[8], bfr[4];
#pragma unroll
      for (int mi = 0; mi < 8; ++mi) {
        int row = wr * 128 + mi * 16 + c16;
        int off = (row * 128 + s * 64 + g * 16) ^ ((row & 7) << 4);
        af[mi] = *(const bf16x8*)((const char*)As[cur] + off);
      }
#pragma unroll
      for (int ni = 0; ni < 4; ++ni) {
        int col = wc * 64 + ni * 16 + c16;
        int off = (col * 128 + s * 64 + g * 16) ^ ((col & 7) << 4);
        bfr[ni] = *(const bf16x8*)((const char*)Bs[cur] + off);
      }
#pragma unroll
      for (int mi = 0; mi < 8; ++mi)
#pragma unroll
        for (int ni = 0; ni < 4; ++ni)
          acc[mi][ni] = __builtin_amdgcn_mfma_f32_16x16x32_bf16(
              af[mi], bfr[ni], acc[mi][ni], 0, 0, 0);
    }
    if (t < 7) {
#pragma unroll
      for (int i = 0; i < 4; ++i) {
        int c = i * 512 + tid, row = c >> 3, kc = c & 7;
        int off = (row * 128 + kc * 16) ^ ((row & 7) << 4);
        *(int4*)((char*)As[cur ^ 1] + off) = av[i];
        *(int4*)((char*)Bs[cur ^ 1] + off) = bv[i];
      }
    }
    __syncthreads();
    cur ^= 1;
  }

#pragma unroll
  for (int mi = 0; mi < 8; ++mi)
#pragma unroll
    for (int ni = 0; ni < 4; ++ni)
#pragma unroll
      for (int j = 0; j < 4; ++j) {
        size_t idx = (size_t)(m0 + wr * 128 + mi * 16 + g * 4 + j) * 512 +
                     n0 + wc * 64 + ni * 16 + c16;
        out[idx] = acc[mi][ni][j] + Xres[idx];
      }
}

// ---------------------------------------------------------------------------
// Fused attention (unchanged, proven). Block = (b,h,128 q), 512 thr.
// ---------------------------------------------------------------------------
__global__ __launch_bounds__(512) void attn_fused(
    const bf16* __restrict__ Qn, const bf16* __restrict__ Kn,
    const bf16* __restrict__ Vt, const float* __restrict__ temp,
    bf16* __restrict__ O) {
  __shared__ __align__(16) char smem[147456];
  // [0,32768) Ksm [256t][64d] | [32768,65536) Vsm [64d][256t]
  // [65536,81920) Qsm [128q][64d] | [81920,147456) Psm [128q][256k]

  const int tid = threadIdx.x;
  const int w = tid >> 6, lane = tid & 63;
  const int g = lane >> 4, c16 = lane & 15;
  const int bx = blockIdx.x;
  const int nt = bx & 31, h = (bx >> 5) & 7, b = bx >> 8;
  const int n0 = nt * 128;

  {
    const bf16* Ksrc = Kn + ((size_t)b * 256) * 512 + h * 64;
#pragma unroll
    for (int it = 0; it < 4; ++it) {
      int c = it * 512 + tid;
      int t = c >> 3, dc = c & 7;
      int4 v = *(const int4*)(Ksrc + (size_t)t * 512 + dc * 8);
      int off = (t * 128 + dc * 16) ^ ((t & 7) << 4);
      *(int4*)(smem + off) = v;
    }
    const bf16* Vsrc = Vt + (size_t)((b * 8 + h) * 64) * 256;
#pragma unroll
    for (int it = 0; it < 4; ++it) {
      int c = it * 512 + tid;
      int d = c >> 5, tc = c & 31;
      int4 v = *(const int4*)(Vsrc + (size_t)d * 256 + tc * 8);
      int off = (d * 512 + tc * 16) ^ ((d & 7) << 4);
      *(int4*)(smem + 32768 + off) = v;
    }
    const bf16* Qsrc = Qn + ((size_t)b * 4096 + n0) * 512 + h * 64;
#pragma unroll
    for (int it = 0; it < 2; ++it) {
      int c = it * 512 + tid;
      int q = c >> 3, dc = c & 7;
      int4 v = *(const int4*)(Qsrc + (size_t)q * 512 + dc * 8);
      int off = (q * 128 + dc * 16) ^ ((q & 7) << 4);
      *(int4*)(smem + 65536 + off) = v;
    }
  }
  __syncthreads();

  const int q = w * 16 + c16;

  f32x4 sacc[16] = {};
  bf16x8 qf[2];
#pragma unroll
  for (int s = 0; s < 2; ++s) {
    int off = (q * 128 + s * 64 + g * 16) ^ ((q & 7) << 4);
    qf[s] = *(const bf16x8*)(smem + 65536 + off);
  }
#pragma unroll
  for (int mi = 0; mi < 16; ++mi) {
#pragma unroll
    for (int s = 0; s < 2; ++s) {
      int t = mi * 16 + c16;
      int off = (t * 128 + s * 64 + g * 16) ^ ((t & 7) << 4);
      bf16x8 kf = *(const bf16x8*)(smem + off);
      sacc[mi] = __builtin_amdgcn_mfma_f32_16x16x32_bf16(kf, qf[s], sacc[mi],
                                                         0, 0, 0);
    }
  }

  float tv = temp[h];
  float mx = -1e30f;
#pragma unroll
  for (int mi = 0; mi < 16; ++mi)
#pragma unroll
    for (int j = 0; j < 4; ++j) {
      sacc[mi][j] *= tv;
      mx = fmaxf(mx, sacc[mi][j]);
    }
  mx = fmaxf(mx, __shfl_xor(mx, 16, 64));
  mx = fmaxf(mx, __shfl_xor(mx, 32, 64));
  float sum = 0.f;
#pragma unroll
  for (int mi = 0; mi < 16; ++mi)
#pragma unroll
    for (int j = 0; j < 4; ++j) {
      float p = __expf(sacc[mi][j] - mx);
      sacc[mi][j] = p;
      sum += p;
    }
  sum += __shfl_xor(sum, 16, 64);
  sum += __shfl_xor(sum, 32, 64);
  float inv = 1.0f / sum;

#pragma unroll
  for (int mi = 0; mi < 16; ++mi) {
    uint2 v;
    v.x = pack2(sacc[mi][0] * inv, sacc[mi][1] * inv);
    v.y = pack2(sacc[mi][2] * inv, sacc[mi][3] * inv);
    int off = (q * 512 + mi * 32 + g * 8) ^ ((q & 7) << 4);
    *(uint2*)(smem + 81920 + off) = v;
  }
  __syncthreads();

  f32x4 oacc[4] = {};
#pragma unroll
  for (int ks = 0; ks < 8; ++ks) {
    int offa = (q * 512 + ks * 64 + g * 16) ^ ((q & 7) << 4);
    bf16x8 pa = *(const bf16x8*)(smem + 81920 + offa);
#pragma unroll
    for (int ni = 0; ni < 4; ++ni) {
      int d = ni * 16 + c16;
      int offb = (d * 512 + ks * 64 + g * 16) ^ ((d & 7) << 4);
      bf16x8 vb = *(const bf16x8*)(smem + 32768 + offb);
      oacc[ni] = __builtin_amdgcn_mfma_f32_16x16x32_bf16(pa, vb, oacc[ni],
                                                         0, 0, 0);
    }
  }

  bf16* Orow = O + ((size_t)b * 4096 + n0 + w * 16) * 512 + h * 64;
#pragma unroll
  for (int ni = 0; ni < 4; ++ni)
#pragma unroll
    for (int j = 0; j < 4; ++j)
      Orow[(size_t)(g * 4 + j) * 512 + ni * 16 + c16] = (bf16)oacc[ni][j];
}

// ---------------------------------------------------------------------------
extern "C" void kernel_launch(void* const* d_in, const int* in_sizes, int n_in,
                              void* d_out, int out_size, void* d_ws,
                              size_t ws_size, hipStream_t stream) {
  const float* X = (const float*)d_in[0];
  const float* S = (const float*)d_in[1];
  const float* Wq = (const float*)d_in[2];
  const float* Wk = (const float*)d_in[3];
  const float* Wv = (const float*)d_in[4];
  const float* Wo = (const float*)d_in[5];
  const float* temp = (const float*)d_in[6];
  float* out = (float*)d_out;

  char* ws = (char*)d_ws;
  bf16* Qws = (bf16*)ws;                      // 32768*512*2 = 33,554,432 B
  bf16* Kws = (bf16*)(ws + 33554432);         //  2048*512*2 =  2,097,152 B
  bf16* Vtws = (bf16*)(ws + 35651584);        //  8*8*64*256*2 = 2,097,152 B
  bf16* Wqb = (bf16*)(ws + 37748736);         //  512*512*2 = 524,288 B each
  bf16* Wkb = (bf16*)(ws + 38273024);
  bf16* Wvb = (bf16*)(ws + 38797312);
  bf16* Wob = (bf16*)(ws + 39321600);

  cvt_all<<<dim3(512), dim3(256), 0, stream>>>(Wq, Wk, Wv, Wo, Wqb, Wkb, Wvb,
                                               Wob);
  proj_all<<<dim3(288), dim3(512), 0, stream>>>(X, S, Wqb, Wkb, Wvb, Qws, Kws,
                                                Vtws);
  attn_fused<<<dim3(2048), dim3(512), 0, stream>>>(Qws, Kws, Vtws, temp, Qws);
  out_gemm<<<dim3(256), dim3(512), 0, stream>>>(Qws, Wob, X, out);
}

// Round 11
// 151.196 us; speedup vs baseline: 1.1098x; 1.1098x over previous
//
#include <hip/hip_runtime.h>
#include <hip/hip_bf16.h>

// MDTA (multi-head cross attention with l2-normed q/k) for MI355X.
// B=8, N=4096, Ktok=256, C=512, H=8, D=64. Inputs f32, output f32.
//
// R8 187.9 -> R9 153.1 -> R10 167.8 (256^2 tiles = 1 block/CU lockstep, bad).
// R11: proj = 128x128/BK64/8-iter dbuf, 2 blocks/CU, reg-staged A+B with
//      issue-early/write-late into XOR-swizzled LDS (conflict-free).
//      out_gemm reverted to R9 exact (128^2/BK32 gload_lds dbuf, 4 blk/CU).
//
// Pipeline: cvt_all -> proj_all (Q,Kn,Vt) -> attn_fused -> out_gemm.

typedef __bf16 bf16;
typedef __attribute__((ext_vector_type(8))) __bf16 bf16x8;
typedef __attribute__((ext_vector_type(4))) float f32x4;

__device__ __forceinline__ void gload_lds16(const void* g, void* l) {
  __builtin_amdgcn_global_load_lds(
      (__attribute__((address_space(1))) void*)g,
      (__attribute__((address_space(3))) void*)l, 16, 0, 0);
}

__device__ __forceinline__ unsigned pack2(float a, float b) {
  unsigned short x = __builtin_bit_cast(unsigned short, (bf16)a);
  unsigned short y = __builtin_bit_cast(unsigned short, (bf16)b);
  return (unsigned)x | ((unsigned)y << 16);
}

// ---------------------------------------------------------------------------
__global__ __launch_bounds__(256) void cvt_all(
    const float* __restrict__ Wq, const float* __restrict__ Wk,
    const float* __restrict__ Wv, const float* __restrict__ Wo,
    bf16* __restrict__ Wqb, bf16* __restrict__ Wkb, bf16* __restrict__ Wvb,
    bf16* __restrict__ Wob) {
  int i = blockIdx.x * 256 + threadIdx.x;  // chunk id, 32768 per weight
  int w = i >> 15, r = i & 32767;
  const float* src = (w == 0) ? Wq : (w == 1) ? Wk : (w == 2) ? Wv : Wo;
  bf16* dst = (w == 0) ? Wqb : (w == 1) ? Wkb : (w == 2) ? Wvb : Wob;
  float4 a = *(const float4*)(src + (size_t)r * 8);
  float4 b = *(const float4*)(src + (size_t)r * 8 + 4);
  uint4 v;
  v.x = pack2(a.x, a.y);
  v.y = pack2(a.z, a.w);
  v.z = pack2(b.x, b.y);
  v.w = pack2(b.z, b.w);
  *(uint4*)(dst + (size_t)r * 8) = v;
}

// ---------------------------------------------------------------------------
// Fused Q/K/V projection. 128x128 tile, 256 thr (4 waves 2x2, 64x64/wave),
// BK=64 (8 iters), LDS double-buffered 64 KB -> 2 blocks/CU. Both operands
// reg-staged (A: f32->bf16 cvt), issue-early/write-late, LDS rows 128B with
// byte ^= ((row&7)<<4) swizzle (attn-proven, conflict-free b128 access).
// ---------------------------------------------------------------------------
__global__ __launch_bounds__(256, 2) void proj_all(
    const float* __restrict__ X, const float* __restrict__ S,
    const bf16* __restrict__ Wqb, const bf16* __restrict__ Wkb,
    const bf16* __restrict__ Wvb, bf16* __restrict__ Q,
    bf16* __restrict__ Kn, bf16* __restrict__ Vt) {
  __shared__ __align__(16) bf16 As[2][128 * 64];
  __shared__ __align__(16) bf16 Bs[2][128 * 64];

  // 1152 = 8 XCDs x 144; consecutive lg (4 n-tiles of one A panel) share XCD.
  const int lg = (blockIdx.x & 7) * 144 + (blockIdx.x >> 3);

  const float* A;
  const bf16* W;
  int m0, kind;  // 0=Q, 1=K, 2=V
  if (lg < 1024) {
    kind = 0; A = X; W = Wqb; m0 = (lg >> 2) * 128;
  } else if (lg < 1088) {
    kind = 1; A = S; W = Wkb; m0 = ((lg - 1024) >> 2) * 128;
  } else {
    kind = 2; A = S; W = Wvb; m0 = ((lg - 1088) >> 2) * 128;
  }
  const int n0 = (lg & 3) * 128;

  const int tid = threadIdx.x;
  const int wid = tid >> 6, lane = tid & 63;
  const int wr = wid >> 1, wc = wid & 1;
  const int g = lane >> 4, c16 = lane & 15;

  f32x4 acc[4][4] = {};

  // staging: 1024 16B-chunks (8 bf16) per operand tile; 4 chunks/thread.
  // chunk cc -> row = cc>>3, k8 = cc&7 (k-offset k8*8).
  // ---- prologue: stage K-tile 0 into buffer 0
#pragma unroll
  for (int i = 0; i < 4; ++i) {
    int cc = i * 256 + tid, row = cc >> 3, k8 = cc & 7;
    int off = (row * 128 + k8 * 16) ^ ((row & 7) << 4);
    const float* s = A + (size_t)(m0 + row) * 512 + k8 * 8;
    float4 x0 = *(const float4*)s, x1 = *(const float4*)(s + 4);
    uint4 v;
    v.x = pack2(x0.x, x0.y); v.y = pack2(x0.z, x0.w);
    v.z = pack2(x1.x, x1.y); v.w = pack2(x1.z, x1.w);
    *(uint4*)((char*)As[0] + off) = v;
    *(int4*)((char*)Bs[0] + off) =
        *(const int4*)(W + (size_t)(n0 + row) * 512 + k8 * 8);
  }
  __syncthreads();

  int cur = 0;
  for (int t = 0; t < 8; ++t) {
    float4 av[8];
    int4 bv[4];
    if (t < 7) {  // issue-early: global loads for tile t+1
      const int kb = (t + 1) * 64;
#pragma unroll
      for (int i = 0; i < 4; ++i) {
        int cc = i * 256 + tid, row = cc >> 3, k8 = cc & 7;
        const float* s = A + (size_t)(m0 + row) * 512 + kb + k8 * 8;
        av[2 * i] = *(const float4*)s;
        av[2 * i + 1] = *(const float4*)(s + 4);
        bv[i] = *(const int4*)(W + (size_t)(n0 + row) * 512 + kb + k8 * 8);
      }
    }

    // compute tile t: 2 k-halves x 16 MFMA
#pragma unroll
    for (int s = 0; s < 2; ++s) {
      bf16x8 af[4], bfr[4];
#pragma unroll
      for (int mi = 0; mi < 4; ++mi) {
        int row = wr * 64 + mi * 16 + c16;
        int off = (row * 128 + s * 64 + g * 16) ^ ((row & 7) << 4);
        af[mi] = *(const bf16x8*)((const char*)As[cur] + off);
      }
#pragma unroll
      for (int ni = 0; ni < 4; ++ni) {
        int col = wc * 64 + ni * 16 + c16;
        int off = (col * 128 + s * 64 + g * 16) ^ ((col & 7) << 4);
        bfr[ni] = *(const bf16x8*)((const char*)Bs[cur] + off);
      }
#pragma unroll
      for (int mi = 0; mi < 4; ++mi)
#pragma unroll
        for (int ni = 0; ni < 4; ++ni)
          acc[mi][ni] = __builtin_amdgcn_mfma_f32_16x16x32_bf16(
              af[mi], bfr[ni], acc[mi][ni], 0, 0, 0);
    }

    if (t < 7) {  // write-late: cvt + swizzled LDS store into back buffer
#pragma unroll
      for (int i = 0; i < 4; ++i) {
        int cc = i * 256 + tid, row = cc >> 3, k8 = cc & 7;
        int off = (row * 128 + k8 * 16) ^ ((row & 7) << 4);
        uint4 v;
        v.x = pack2(av[2 * i].x, av[2 * i].y);
        v.y = pack2(av[2 * i].z, av[2 * i].w);
        v.z = pack2(av[2 * i + 1].x, av[2 * i + 1].y);
        v.w = pack2(av[2 * i + 1].z, av[2 * i + 1].w);
        *(uint4*)((char*)As[cur ^ 1] + off) = v;
        *(int4*)((char*)Bs[cur ^ 1] + off) = bv[i];
      }
    }
    __syncthreads();
    cur ^= 1;
  }

  // ---- epilogue. C/D frag: col = lane&15, row = (lane>>4)*4 + j   [m89]
  if (kind != 2) {
    bf16* C = (kind == 0) ? Q : Kn;
    // l2 norm over the wave's 64 cols (= exactly one head).
#pragma unroll
    for (int mi = 0; mi < 4; ++mi) {
      float ss[4];
#pragma unroll
      for (int j = 0; j < 4; ++j) {
        float s = 0.f;
#pragma unroll
        for (int ni = 0; ni < 4; ++ni) {
          float v = acc[mi][ni][j];
          s += v * v;
        }
        ss[j] = s;
      }
#pragma unroll
      for (int msk = 1; msk < 16; msk <<= 1)
#pragma unroll
        for (int j = 0; j < 4; ++j) ss[j] += __shfl_xor(ss[j], msk, 64);
      float inv[4];
#pragma unroll
      for (int j = 0; j < 4; ++j) inv[j] = rsqrtf(fmaxf(ss[j], 1e-24f));
#pragma unroll
      for (int ni = 0; ni < 4; ++ni)
#pragma unroll
        for (int j = 0; j < 4; ++j) {
          size_t idx = (size_t)(m0 + wr * 64 + mi * 16 + g * 4 + j) * 512 +
                       n0 + wc * 64 + ni * 16 + c16;
          C[idx] = (bf16)(acc[mi][ni][j] * inv[j]);
        }
    }
  } else {
    // transposed store into Vt[b][h][d][t] (M=2048): 4 j = 4 tokens -> 8B
#pragma unroll
    for (int mi = 0; mi < 4; ++mi) {
      int m = m0 + wr * 64 + mi * 16 + g * 4;  // +j
      int b = m >> 8, tt = m & 255;
#pragma unroll
      for (int ni = 0; ni < 4; ++ni) {
        int col = n0 + wc * 64 + ni * 16 + c16;
        int h = col >> 6, d = col & 63;
        uint2 v;
        v.x = pack2(acc[mi][ni][0], acc[mi][ni][1]);
        v.y = pack2(acc[mi][ni][2], acc[mi][ni][3]);
        *(uint2*)(Vt + ((size_t)((b * 8 + h) * 64 + d) * 256 + tt)) = v;
      }
    }
  }
}

// ---------------------------------------------------------------------------
// out = X + O @ Wo^T, f32 output. R9-exact structure: 128x128, BK=32,
// 2-phase gload_lds double-buffer, ~4 blocks/CU, XCD swizzle.
// ---------------------------------------------------------------------------
__global__ __launch_bounds__(256) void out_gemm(
    const bf16* __restrict__ O, const bf16* __restrict__ Wob,
    const float* __restrict__ Xres, float* __restrict__ out) {
  __shared__ __align__(16) bf16 As[2][128 * 32];
  __shared__ __align__(16) bf16 Bs[2][128 * 32];

  const int lg = (blockIdx.x & 7) * 128 + (blockIdx.x >> 3);  // XCD swizzle
  const int m0 = (lg >> 2) * 128, n0 = (lg & 3) * 128;

  const int tid = threadIdx.x;
  const int wid = tid >> 6, lane = tid & 63;
  const int wr = wid >> 1, wc = wid & 1;
  const int g = lane >> 4, c16 = lane & 15;
  const int c0 = tid, c1 = 256 + tid;
  const int r0 = c0 >> 2, cc0 = c0 & 3;
  const int r1 = c1 >> 2, cc1 = c1 & 3;

  f32x4 acc[4][4] = {};

  gload_lds16(O + (size_t)(m0 + r0) * 512 + cc0 * 8, As[0] + (tid & ~63) * 8);
  gload_lds16(O + (size_t)(m0 + r1) * 512 + cc1 * 8,
              As[0] + (256 + (tid & ~63)) * 8);
  gload_lds16(Wob + (size_t)(n0 + r0) * 512 + cc0 * 8,
              Bs[0] + (tid & ~63) * 8);
  gload_lds16(Wob + (size_t)(n0 + r1) * 512 + cc1 * 8,
              Bs[0] + (256 + (tid & ~63)) * 8);
  __syncthreads();

  int cur = 0;
  for (int t = 0; t < 16; ++t) {
    const int kb = (t + 1) * 32;
    if (t < 15) {
      gload_lds16(O + (size_t)(m0 + r0) * 512 + kb + cc0 * 8,
                  As[cur ^ 1] + (tid & ~63) * 8);
      gload_lds16(O + (size_t)(m0 + r1) * 512 + kb + cc1 * 8,
                  As[cur ^ 1] + (256 + (tid & ~63)) * 8);
      gload_lds16(Wob + (size_t)(n0 + r0) * 512 + kb + cc0 * 8,
                  Bs[cur ^ 1] + (tid & ~63) * 8);
      gload_lds16(Wob + (size_t)(n0 + r1) * 512 + kb + cc1 * 8,
                  Bs[cur ^ 1] + (256 + (tid & ~63)) * 8);
    }
    bf16x8 af[4], bfr[4];
#pragma unroll
    for (int mi = 0; mi < 4; ++mi)
      af[mi] =
          *(const bf16x8*)(As[cur] + (wr * 64 + mi * 16 + c16) * 32 + g * 8);
#pragma unroll
    for (int ni = 0; ni < 4; ++ni)
      bfr[ni] =
          *(const bf16x8*)(Bs[cur] + (wc * 64 + ni * 16 + c16) * 32 + g * 8);
#pragma unroll
    for (int mi = 0; mi < 4; ++mi)
#pragma unroll
      for (int ni = 0; ni < 4; ++ni)
        acc[mi][ni] = __builtin_amdgcn_mfma_f32_16x16x32_bf16(
            af[mi], bfr[ni], acc[mi][ni], 0, 0, 0);
    __syncthreads();
    cur ^= 1;
  }

#pragma unroll
  for (int mi = 0; mi < 4; ++mi)
#pragma unroll
    for (int ni = 0; ni < 4; ++ni)
#pragma unroll
      for (int j = 0; j < 4; ++j) {
        size_t idx = (size_t)(m0 + wr * 64 + mi * 16 + g * 4 + j) * 512 + n0 +
                     wc * 64 + ni * 16 + c16;
        out[idx] = acc[mi][ni][j] + Xres[idx];
      }
}

// ---------------------------------------------------------------------------
// Fused attention (unchanged, proven). Block = (b,h,128 q), 512 thr.
// ---------------------------------------------------------------------------
__global__ __launch_bounds__(512) void attn_fused(
    const bf16* __restrict__ Qn, const bf16* __restrict__ Kn,
    const bf16* __restrict__ Vt, const float* __restrict__ temp,
    bf16* __restrict__ O) {
  __shared__ __align__(16) char smem[147456];
  // [0,32768) Ksm [256t][64d] | [32768,65536) Vsm [64d][256t]
  // [65536,81920) Qsm [128q][64d] | [81920,147456) Psm [128q][256k]

  const int tid = threadIdx.x;
  const int w = tid >> 6, lane = tid & 63;
  const int g = lane >> 4, c16 = lane & 15;
  const int bx = blockIdx.x;
  const int nt = bx & 31, h = (bx >> 5) & 7, b = bx >> 8;
  const int n0 = nt * 128;

  {
    const bf16* Ksrc = Kn + ((size_t)b * 256) * 512 + h * 64;
#pragma unroll
    for (int it = 0; it < 4; ++it) {
      int c = it * 512 + tid;
      int t = c >> 3, dc = c & 7;
      int4 v = *(const int4*)(Ksrc + (size_t)t * 512 + dc * 8);
      int off = (t * 128 + dc * 16) ^ ((t & 7) << 4);
      *(int4*)(smem + off) = v;
    }
    const bf16* Vsrc = Vt + (size_t)((b * 8 + h) * 64) * 256;
#pragma unroll
    for (int it = 0; it < 4; ++it) {
      int c = it * 512 + tid;
      int d = c >> 5, tc = c & 31;
      int4 v = *(const int4*)(Vsrc + (size_t)d * 256 + tc * 8);
      int off = (d * 512 + tc * 16) ^ ((d & 7) << 4);
      *(int4*)(smem + 32768 + off) = v;
    }
    const bf16* Qsrc = Qn + ((size_t)b * 4096 + n0) * 512 + h * 64;
#pragma unroll
    for (int it = 0; it < 2; ++it) {
      int c = it * 512 + tid;
      int q = c >> 3, dc = c & 7;
      int4 v = *(const int4*)(Qsrc + (size_t)q * 512 + dc * 8);
      int off = (q * 128 + dc * 16) ^ ((q & 7) << 4);
      *(int4*)(smem + 65536 + off) = v;
    }
  }
  __syncthreads();

  const int q = w * 16 + c16;

  f32x4 sacc[16] = {};
  bf16x8 qf[2];
#pragma unroll
  for (int s = 0; s < 2; ++s) {
    int off = (q * 128 + s * 64 + g * 16) ^ ((q & 7) << 4);
    qf[s] = *(const bf16x8*)(smem + 65536 + off);
  }
#pragma unroll
  for (int mi = 0; mi < 16; ++mi) {
#pragma unroll
    for (int s = 0; s < 2; ++s) {
      int t = mi * 16 + c16;
      int off = (t * 128 + s * 64 + g * 16) ^ ((t & 7) << 4);
      bf16x8 kf = *(const bf16x8*)(smem + off);
      sacc[mi] = __builtin_amdgcn_mfma_f32_16x16x32_bf16(kf, qf[s], sacc[mi],
                                                         0, 0, 0);
    }
  }

  float tv = temp[h];
  float mx = -1e30f;
#pragma unroll
  for (int mi = 0; mi < 16; ++mi)
#pragma unroll
    for (int j = 0; j < 4; ++j) {
      sacc[mi][j] *= tv;
      mx = fmaxf(mx, sacc[mi][j]);
    }
  mx = fmaxf(mx, __shfl_xor(mx, 16, 64));
  mx = fmaxf(mx, __shfl_xor(mx, 32, 64));
  float sum = 0.f;
#pragma unroll
  for (int mi = 0; mi < 16; ++mi)
#pragma unroll
    for (int j = 0; j < 4; ++j) {
      float p = __expf(sacc[mi][j] - mx);
      sacc[mi][j] = p;
      sum += p;
    }
  sum += __shfl_xor(sum, 16, 64);
  sum += __shfl_xor(sum, 32, 64);
  float inv = 1.0f / sum;

#pragma unroll
  for (int mi = 0; mi < 16; ++mi) {
    uint2 v;
    v.x = pack2(sacc[mi][0] * inv, sacc[mi][1] * inv);
    v.y = pack2(sacc[mi][2] * inv, sacc[mi][3] * inv);
    int off = (q * 512 + mi * 32 + g * 8) ^ ((q & 7) << 4);
    *(uint2*)(smem + 81920 + off) = v;
  }
  __syncthreads();

  f32x4 oacc[4] = {};
#pragma unroll
  for (int ks = 0; ks < 8; ++ks) {
    int offa = (q * 512 + ks * 64 + g * 16) ^ ((q & 7) << 4);
    bf16x8 pa = *(const bf16x8*)(smem + 81920 + offa);
#pragma unroll
    for (int ni = 0; ni < 4; ++ni) {
      int d = ni * 16 + c16;
      int offb = (d * 512 + ks * 64 + g * 16) ^ ((d & 7) << 4);
      bf16x8 vb = *(const bf16x8*)(smem + 32768 + offb);
      oacc[ni] = __builtin_amdgcn_mfma_f32_16x16x32_bf16(pa, vb, oacc[ni],
                                                         0, 0, 0);
    }
  }

  bf16* Orow = O + ((size_t)b * 4096 + n0 + w * 16) * 512 + h * 64;
#pragma unroll
  for (int ni = 0; ni < 4; ++ni)
#pragma unroll
    for (int j = 0; j < 4; ++j)
      Orow[(size_t)(g * 4 + j) * 512 + ni * 16 + c16] = (bf16)oacc[ni][j];
}

// ---------------------------------------------------------------------------
extern "C" void kernel_launch(void* const* d_in, const int* in_sizes, int n_in,
                              void* d_out, int out_size, void* d_ws,
                              size_t ws_size, hipStream_t stream) {
  const float* X = (const float*)d_in[0];
  const float* S = (const float*)d_in[1];
  const float* Wq = (const float*)d_in[2];
  const float* Wk = (const float*)d_in[3];
  const float* Wv = (const float*)d_in[4];
  const float* Wo = (const float*)d_in[5];
  const float* temp = (const float*)d_in[6];
  float* out = (float*)d_out;

  char* ws = (char*)d_ws;
  bf16* Qws = (bf16*)ws;                      // 32768*512*2 = 33,554,432 B
  bf16* Kws = (bf16*)(ws + 33554432);         //  2048*512*2 =  2,097,152 B
  bf16* Vtws = (bf16*)(ws + 35651584);        //  8*8*64*256*2 = 2,097,152 B
  bf16* Wqb = (bf16*)(ws + 37748736);         //  512*512*2 = 524,288 B each
  bf16* Wkb = (bf16*)(ws + 38273024);
  bf16* Wvb = (bf16*)(ws + 38797312);
  bf16* Wob = (bf16*)(ws + 39321600);

  cvt_all<<<dim3(512), dim3(256), 0, stream>>>(Wq, Wk, Wv, Wo, Wqb, Wkb, Wvb,
                                               Wob);
  proj_all<<<dim3(1152), dim3(256), 0, stream>>>(X, S, Wqb, Wkb, Wvb, Qws,
                                                 Kws, Vtws);
  attn_fused<<<dim3(2048), dim3(512), 0, stream>>>(Qws, Kws, Vtws, temp, Qws);
  out_gemm<<<dim3(1024), dim3(256), 0, stream>>>(Qws, Wob, X, out);
}